// Round 14
// baseline (1690.146 us; speedup 1.0000x reference)
//
#include <hip/hip_runtime.h>

#define TF 8      // T (edge types)
#define FD 32     // F (features)
#define WS 33     // padded LDS stride for Wt (bank-conflict-free, proven r10)
#define EPSV 1e-5f

__device__ __forceinline__ void atomAddF(float* p, float v) {
#if defined(__HIP_PLATFORM_AMD__)
    unsafeAtomicAdd(p, v);   // hardware global_atomic_add_f32
#else
    atomicAdd(p, v);
#endif
}

// f32 -> bf16 (RNE)
__device__ __forceinline__ unsigned int f2bfu(float x) {
    unsigned int u = __float_as_uint(x);
    return (u + 0x7FFFu + ((u >> 16) & 1u)) >> 16;
}
__device__ __forceinline__ float bfx(unsigned int w, int hi) {
    return __uint_as_float(hi ? (w & 0xFFFF0000u) : (w << 16));
}

// ---------------------------------------------------------------- CSR build
__global__ __launch_bounds__(256) void hist_kernel(
    const int* __restrict__ dst, int* __restrict__ counts, int E)
{
    int e = blockIdx.x * 256 + threadIdx.x;
    if (e < E) atomicAdd(&counts[dst[e]], 1);
}

__global__ __launch_bounds__(1024) void scan_kernel(
    const int* __restrict__ counts, int* __restrict__ rowptr,
    int* __restrict__ cursor, int Nn)
{
    __shared__ int totals[1024];
    int tid = threadIdx.x;
    int per = (Nn + 1023) >> 10;
    int start = tid * per;
    int end = min(start + per, Nn);
    if (end < start) end = start;
    int s = 0;
    for (int i = start; i < end; ++i) s += counts[i];
    totals[tid] = s;
    __syncthreads();
    for (int off = 1; off < 1024; off <<= 1) {
        int t2 = (tid >= off) ? totals[tid - off] : 0;
        __syncthreads();
        totals[tid] += t2;
        __syncthreads();
    }
    int running = totals[tid] - s;
    for (int i = start; i < end; ++i) {
        rowptr[i] = running;
        cursor[i] = running;
        running += counts[i];
    }
    if (tid == 1023) rowptr[Nn] = totals[1023];
}

// ssrc[j] = src of j-th dst-sorted edge; wsb[j] = 8 bf16 weights (t0..t7)
__global__ __launch_bounds__(256) void fillA_kernel(
    const int* __restrict__ src, const int* __restrict__ dst,
    const float* __restrict__ w, int* __restrict__ cursor,
    int* __restrict__ ssrc, uint4* __restrict__ wsb, int E)
{
    int e = blockIdx.x * 256 + threadIdx.x;
    if (e >= E) return;
    int d = dst[e];
    int j = atomicAdd(&cursor[d], 1);
    ssrc[j] = src[e];
    uint4 p;
    p.x = f2bfu(w[(size_t)0 * E + e]) | (f2bfu(w[(size_t)1 * E + e]) << 16);
    p.y = f2bfu(w[(size_t)2 * E + e]) | (f2bfu(w[(size_t)3 * E + e]) << 16);
    p.z = f2bfu(w[(size_t)4 * E + e]) | (f2bfu(w[(size_t)5 * E + e]) << 16);
    p.w = f2bfu(w[(size_t)6 * E + e]) | (f2bfu(w[(size_t)7 * E + e]) << 16);
    wsb[j] = p;
}

// -------- aggregate (depth-2 pipeline, r11-proven) + norm-on-the-fly + GEMM
//          + LN-stats + LAST-BLOCK coef finalize (replaces finalize launch).
// MODE 0: hf (N,F) f32, broadcast over t. MODE 1: hb bf16-packed raw,
// apply relu(x*cA[f]+cB[f]). OUTB 1: bf16-packed out; OUTB 0: f32 out.
template <int MODE, int OUTB>
__global__ __launch_bounds__(256) void agg_gemm9_kernel(
    const float* __restrict__ hf, const uint4* __restrict__ hb,
    const float* __restrict__ coefIn,
    const int* __restrict__ rowptr, const int* __restrict__ ssrc,
    const uint4* __restrict__ wsb,
    const float* __restrict__ W, const float* __restrict__ bias,
    unsigned int* __restrict__ outU, float* __restrict__ outF,
    float* __restrict__ stats, int* __restrict__ done,
    const float* __restrict__ gamma, const float* __restrict__ beta,
    float* __restrict__ coefOut, float inv_count)
{
    __shared__ float Wt[FD * WS];          // Wt[k*33 + o], padded
    __shared__ float red[512];
    __shared__ float pacc[8 * TF * FD];    // [slot][t][f]
    __shared__ int lastFlag;
    int tid = threadIdx.x;
    int slot = tid >> 5, f = tid & 31;
    {   // stage W transposed; padded stride -> conflict-free banks
        int ff = tid & 31;
        Wt[ff * WS + (tid >> 5)] = W[tid];
        Wt[ff * WS + ((tid + 256) >> 5)] = W[tid + 256];
        Wt[ff * WS + ((tid + 512) >> 5)] = W[tid + 512];
        Wt[ff * WS + ((tid + 768) >> 5)] = W[tid + 768];
    }
    float cA = 0.f, cB = 0.f;
    if (MODE == 1) { cA = coefIn[f]; cB = coefIn[FD + f]; }

    int node = blockIdx.x;
    int rs = rowptr[node], re = rowptr[node + 1];

    float acc[TF];
    #pragma unroll
    for (int t = 0; t < TF; ++t) acc[t] = 0.f;

    // depth-2 pipelined gather (proven r11)
    int j = rs + slot;
    if (j < re) {
        int s0 = ssrc[j];
        int j1 = j + 8;
        int s1 = (j1 < re) ? ssrc[j1] : 0;
        uint4 wp = wsb[j];
        float  hf0 = 0.f; uint4 hp0 = {0u,0u,0u,0u};
        if (MODE == 0) hf0 = hf[(size_t)s0 * FD + f];
        else           hp0 = hb[(size_t)s0 * FD + f];

        for (; j < re; j += 8, j1 += 8) {
            int j2 = j1 + 8;
            int s2 = (j2 < re) ? ssrc[j2] : 0;
            uint4 wp_n = {0u,0u,0u,0u};
            if (j1 < re) wp_n = wsb[j1];
            float hf_n = 0.f; uint4 hp_n = {0u,0u,0u,0u};
            if (MODE == 0) hf_n = hf[(size_t)s1 * FD + f];
            else           hp_n = hb[(size_t)s1 * FD + f];

            unsigned int ww[4] = { wp.x, wp.y, wp.z, wp.w };
            if (MODE == 0) {
                #pragma unroll
                for (int t = 0; t < TF; ++t)
                    acc[t] = fmaf(bfx(ww[t >> 1], t & 1), hf0, acc[t]);
            } else {
                unsigned int hw[4] = { hp0.x, hp0.y, hp0.z, hp0.w };
                #pragma unroll
                for (int t = 0; t < TF; ++t) {
                    float hr = bfx(hw[t >> 1], t & 1);
                    float hn = fmaxf(0.f, fmaf(hr, cA, cB));
                    acc[t] = fmaf(bfx(ww[t >> 1], t & 1), hn, acc[t]);
                }
            }
            s1 = s2; wp = wp_n; hf0 = hf_n; hp0 = hp_n;
        }
    }

    // cross-slot reduction: pacc[slot][t][f]
    #pragma unroll
    for (int t = 0; t < TF; ++t)
        pacc[slot * (TF * FD) + t * FD + f] = acc[t];
    __syncthreads();
    int t2 = tid >> 5;                      // reinterpret thread as (t, f)
    float asum = 0.f;
    #pragma unroll
    for (int sl = 0; sl < 8; ++sl)
        asum += pacc[sl * (TF * FD) + t2 * FD + f];
    red[tid] = asum;
    __syncthreads();

    float oval = bias[f];
    #pragma unroll
    for (int k = 0; k < FD; ++k)
        oval = fmaf(red[t2 * FD + k], Wt[k * WS + f], oval);

    if (!OUTB) {
        outF[(size_t)node * (TF * FD) + tid] = oval;   // raw f32
    } else {
        // bf16 pack via wave shuffle (validated r12/r13): lane^32 = t-pair
        float pv = __shfl_xor(oval, 32);
        if ((tid & 63) < 32) {             // even-t2 lanes
            unsigned int lo = f2bfu(oval), hi = f2bfu(pv);
            int w = tid >> 6;              // q = t2>>1 = wave index
            outU[(size_t)node * 128 + f * 4 + w] = lo | (hi << 16);
        }
    }

    __syncthreads();                        // done reading red/Wt
    red[tid] = oval;
    red[256 + tid] = oval * oval;
    __syncthreads();
    #pragma unroll
    for (int stride = 128; stride >= 32; stride >>= 1) {
        if (tid < stride) {
            red[tid] += red[tid + stride];
            red[256 + tid] += red[256 + tid + stride];
        }
        __syncthreads();
    }
    if (tid < 32) {
        int slot2 = blockIdx.x & 31;
        atomAddF(&stats[slot2 * 64 + tid], red[tid]);
        atomAddF(&stats[slot2 * 64 + 32 + tid], red[256 + tid]);
    }

    // last-block finalize: exactly one block reduces stats -> coefOut
    if (tid == 0) {
        __threadfence();                    // release our stats atomics
        int v = __hip_atomic_fetch_add(done, 1, __ATOMIC_ACQ_REL,
                                       __HIP_MEMORY_SCOPE_AGENT);
        lastFlag = (v == (int)gridDim.x - 1);
    }
    __syncthreads();
    if (lastFlag && tid < 32) {
        float s = 0.f, sq = 0.f;
        #pragma unroll
        for (int k = 0; k < 32; ++k) {
            s  += __hip_atomic_load(&stats[k * 64 + tid],
                                    __ATOMIC_RELAXED, __HIP_MEMORY_SCOPE_AGENT);
            sq += __hip_atomic_load(&stats[k * 64 + 32 + tid],
                                    __ATOMIC_RELAXED, __HIP_MEMORY_SCOPE_AGENT);
        }
        float mean = s * inv_count;
        float var  = sq * inv_count - mean * mean;
        float sc   = gamma[tid] * rsqrtf(var + EPSV);
        coefOut[tid]      = sc;
        coefOut[FD + tid] = beta[tid] - mean * sc;
    }
}

__global__ __launch_bounds__(256) void norm_relu_kernel(
    float* __restrict__ x, const float* __restrict__ coef, int n4)
{
    int gid = blockIdx.x * 256 + threadIdx.x;
    if (gid >= n4) return;
    float4 v = ((const float4*)x)[gid];
    int o = (gid * 4) & 31;
    float4 r;
    r.x = fmaxf(0.f, fmaf(v.x, coef[o],     coef[32 + o]));
    r.y = fmaxf(0.f, fmaf(v.y, coef[o + 1], coef[33 + o]));
    r.z = fmaxf(0.f, fmaf(v.z, coef[o + 2], coef[34 + o]));
    r.w = fmaxf(0.f, fmaf(v.w, coef[o + 3], coef[35 + o]));
    ((float4*)x)[gid] = r;
}

// ------------------------------------------------ fallback (atomic scatter)
__global__ __launch_bounds__(256) void scatter0_kernel(
    const float* __restrict__ h, const float* __restrict__ w,
    const int* __restrict__ src, const int* __restrict__ dst,
    float* __restrict__ agg, int E)
{
    int gid = blockIdx.x * 256 + threadIdx.x;
    int e = gid >> 5;
    if (e >= E) return;
    int f = gid & 31;
    int s = src[e], d = dst[e];
    float hv = h[(size_t)s * FD + f];
    float* aggd = agg + (size_t)d * (TF * FD) + f;
    #pragma unroll
    for (int t = 0; t < TF; ++t)
        atomAddF(aggd + t * FD, w[(size_t)t * E + e] * hv);
}

__global__ __launch_bounds__(256) void scatterL_kernel(
    const float* __restrict__ h, const float* __restrict__ w,
    const int* __restrict__ src, const int* __restrict__ dst,
    float* __restrict__ agg, int E)
{
    int gid = blockIdx.x * 256 + threadIdx.x;
    int e = gid >> 5;
    if (e >= E) return;
    int f = gid & 31;
    int s = src[e], d = dst[e];
    const float* hs = h + (size_t)s * (TF * FD) + f;
    float* aggd = agg + (size_t)d * (TF * FD) + f;
    #pragma unroll
    for (int t = 0; t < TF; ++t)
        atomAddF(aggd + t * FD, w[(size_t)t * E + e] * hs[t * FD]);
}

__global__ __launch_bounds__(256) void gemm_stats_kernel(
    const float* __restrict__ agg, const float* __restrict__ W,
    const float* __restrict__ bias, float* __restrict__ out,
    float* __restrict__ stats, int nrows)
{
    __shared__ float Wt[FD * FD];
    __shared__ float rows[8 * FD];
    int tid = threadIdx.x;
    for (int i = tid; i < FD * FD; i += 256) {
        int o = i >> 5, f = i & 31;
        Wt[f * FD + o] = W[i];
    }
    int o = tid & 31;
    int r = tid >> 5;
    float b = bias[o];
    float sum = 0.f, sumsq = 0.f;
    int ngroups = (nrows + 7) >> 3;
    for (int g = blockIdx.x; g < ngroups; g += gridDim.x) {
        int row0 = g * 8;
        __syncthreads();
        int idx = row0 * FD + tid;
        rows[tid] = (idx < nrows * FD) ? agg[idx] : 0.f;
        __syncthreads();
        int row = row0 + r;
        if (row < nrows) {
            float acc = b;
            #pragma unroll
            for (int f2 = 0; f2 < FD; ++f2)
                acc = fmaf(rows[r * FD + f2], Wt[f2 * FD + o], acc);
            out[(size_t)row * FD + o] = acc;
            sum += acc;
            sumsq += acc * acc;
        }
    }
    __syncthreads();
    rows[tid] = sum;
    Wt[tid] = sumsq;
    __syncthreads();
    for (int stride = 128; stride >= 32; stride >>= 1) {
        if (tid < stride) { rows[tid] += rows[tid + stride]; Wt[tid] += Wt[tid + stride]; }
        __syncthreads();
    }
    if (tid < 32) {
        int slot = blockIdx.x & 31;
        atomAddF(&stats[slot * 64 + tid], rows[tid]);
        atomAddF(&stats[slot * 64 + 32 + tid], Wt[tid]);
    }
}

__global__ void finalize_kernel(const float* __restrict__ stats,
                                const float* __restrict__ gamma,
                                const float* __restrict__ beta,
                                float* __restrict__ coef, float inv_count)
{
    int o = threadIdx.x;
    float s = 0.f, sq = 0.f;
    #pragma unroll
    for (int k = 0; k < 32; ++k) { s += stats[k * 64 + o]; sq += stats[k * 64 + 32 + o]; }
    float mean = s * inv_count;
    float var  = sq * inv_count - mean * mean;
    float sc   = gamma[o] * rsqrtf(var + EPSV);
    coef[o]      = sc;
    coef[FD + o] = beta[o] - mean * sc;
}

// ----------------------------------------------------------------- launch
extern "C" void kernel_launch(void* const* d_in, const int* in_sizes, int n_in,
                              void* d_out, int out_size, void* d_ws, size_t ws_size,
                              hipStream_t stream)
{
    const float* nf  = (const float*)d_in[0];
    const float* wgt = (const float*)d_in[1];
    const int*   src = (const int*)d_in[2];
    const int*   dst = (const int*)d_in[3];
    const float* Ws  = (const float*)d_in[4];
    const float* bs  = (const float*)d_in[5];
    const float* gam = (const float*)d_in[6];
    const float* bet = (const float*)d_in[7];

    int E  = in_sizes[2];
    int Nn = in_sizes[0] / FD;
    int nrows = Nn * TF;
    int n4 = nrows * FD / 4;
    float inv_count = 1.0f / (float)nrows;
    float* out = (float*)d_out;

    // layout (int units): counts Nn | stats 3*2048 | done 8 | coef 3*64 |
    // cursor Nn | rowptr Nn+4 | ssrc E | wsb 4E(uint4) | hb0 128Nn | hb1 128Nn
    size_t offCounts = 0;
    size_t offStats  = offCounts + (size_t)Nn;   // memset covers counts..done
    size_t offDone   = offStats + 3 * 2048;
    size_t offCoef   = offDone + 8;
    size_t offCursor = offCoef + 3 * 64;
    size_t offRowptr = offCursor + (size_t)Nn;
    size_t offSsrc   = offRowptr + (size_t)Nn + 4;
    size_t offWsb    = (offSsrc + (size_t)E + 3) & ~(size_t)3;   // 16B align
    size_t offHb0    = offWsb + 4 * (size_t)E;
    size_t offHb1    = offHb0 + 128 * (size_t)Nn;
    size_t needW     = (offHb1 + 128 * (size_t)Nn) * 4;

    int eb = (E + 255) / 256;

    if (ws_size >= needW) {
        int*          base   = (int*)d_ws;
        int*          counts = base + offCounts;
        float*        stats  = (float*)(base + offStats);
        int*          done   = base + offDone;
        float*        coef   = (float*)(base + offCoef);
        int*          cursor = base + offCursor;
        int*          rowptr = base + offRowptr;
        int*          ssrc   = base + offSsrc;
        uint4*        wsb    = (uint4*)(base + offWsb);
        unsigned int* hb0    = (unsigned int*)(base + offHb0);
        unsigned int* hb1    = (unsigned int*)(base + offHb1);

        // one memset: counts + stats + done (adjacent)
        hipMemsetAsync(counts, 0, ((size_t)Nn + 3 * 2048 + 8) * sizeof(int), stream);
        hist_kernel<<<eb, 256, 0, stream>>>(dst, counts, E);
        scan_kernel<<<1, 1024, 0, stream>>>(counts, rowptr, cursor, Nn);
        fillA_kernel<<<eb, 256, 0, stream>>>(src, dst, wgt, cursor, ssrc, wsb, E);

        // L0: nf(f32) -> hb0 (bf16 raw); coef0 by last block
        agg_gemm9_kernel<0, 1><<<Nn, 256, 0, stream>>>(
            nf, nullptr, nullptr, rowptr, ssrc, wsb, Ws, bs,
            hb0, nullptr, stats, done, gam, bet, coef, inv_count);
        // L1: hb0 -> hb1 (bf16 raw), norm0 via coef0; coef1 by last block
        agg_gemm9_kernel<1, 1><<<Nn, 256, 0, stream>>>(
            nullptr, (const uint4*)hb0, coef, rowptr, ssrc, wsb,
            Ws + FD * FD, bs + FD, hb1, nullptr, stats + 2048, done + 1,
            gam + FD, bet + FD, coef + 64, inv_count);
        // L2: hb1 -> out (f32 raw), norm1 via coef1; coef2 by last block
        agg_gemm9_kernel<1, 0><<<Nn, 256, 0, stream>>>(
            nullptr, (const uint4*)hb1, coef + 64, rowptr, ssrc, wsb,
            Ws + 2 * FD * FD, bs + 2 * FD, nullptr, out, stats + 2 * 2048,
            done + 2, gam + 2 * FD, bet + 2 * FD, coef + 2 * 64, inv_count);
        // final norm+relu via coef2
        norm_relu_kernel<<<(n4 + 255) / 256, 256, 0, stream>>>(out, coef + 2 * 64, n4);
    } else {
        // fallback: round-0 atomic scatter path (proven)
        float* agg   = (float*)d_ws;
        float* stats = agg + (size_t)nrows * FD;
        float* coef  = stats + 2048;
        int scatterBlocks = (E * 32 + 255) / 256;
        for (int l = 0; l < 3; ++l) {
            hipMemsetAsync(agg, 0, (size_t)nrows * FD * sizeof(float), stream);
            hipMemsetAsync(stats, 0, 2048 * sizeof(float), stream);
            if (l == 0)
                scatter0_kernel<<<scatterBlocks, 256, 0, stream>>>(nf, wgt, src, dst, agg, E);
            else
                scatterL_kernel<<<scatterBlocks, 256, 0, stream>>>(out, wgt, src, dst, agg, E);
            gemm_stats_kernel<<<2048, 256, 0, stream>>>(
                agg, Ws + l * FD * FD, bs + l * FD, out, stats, nrows);
            finalize_kernel<<<1, 32, 0, stream>>>(
                stats, gam + l * FD, bet + l * FD, coef, inv_count);
            norm_relu_kernel<<<(n4 + 255) / 256, 256, 0, stream>>>(out, coef, n4);
        }
    }
}

// Round 15
// 218.209 us; speedup vs baseline: 7.7455x; 7.7455x over previous
//
#include <hip/hip_runtime.h>

#define TF 8      // T (edge types)
#define FD 32     // F (features)
#define WS 33     // padded LDS stride for Wt (bank-conflict-free, proven r10)
#define EPSV 1e-5f

__device__ __forceinline__ void atomAddF(float* p, float v) {
#if defined(__HIP_PLATFORM_AMD__)
    unsafeAtomicAdd(p, v);   // hardware global_atomic_add_f32
#else
    atomicAdd(p, v);
#endif
}

// f32 -> bf16 (RNE)
__device__ __forceinline__ unsigned int f2bfu(float x) {
    unsigned int u = __float_as_uint(x);
    return (u + 0x7FFFu + ((u >> 16) & 1u)) >> 16;
}
__device__ __forceinline__ float bfx(unsigned int w, int hi) {
    return __uint_as_float(hi ? (w & 0xFFFF0000u) : (w << 16));
}

// ---------------------------------------------------------------- CSR build
__global__ __launch_bounds__(256) void hist_kernel(
    const int* __restrict__ dst, int* __restrict__ counts, int E)
{
    int e = blockIdx.x * 256 + threadIdx.x;
    if (e < E) atomicAdd(&counts[dst[e]], 1);
}

__global__ __launch_bounds__(1024) void scan_kernel(
    const int* __restrict__ counts, int* __restrict__ rowptr,
    int* __restrict__ cursor, int Nn)
{
    __shared__ int totals[1024];
    int tid = threadIdx.x;
    int per = (Nn + 1023) >> 10;
    int start = tid * per;
    int end = min(start + per, Nn);
    if (end < start) end = start;
    int s = 0;
    for (int i = start; i < end; ++i) s += counts[i];
    totals[tid] = s;
    __syncthreads();
    for (int off = 1; off < 1024; off <<= 1) {
        int t2 = (tid >= off) ? totals[tid - off] : 0;
        __syncthreads();
        totals[tid] += t2;
        __syncthreads();
    }
    int running = totals[tid] - s;
    for (int i = start; i < end; ++i) {
        rowptr[i] = running;
        cursor[i] = running;
        running += counts[i];
    }
    if (tid == 1023) rowptr[Nn] = totals[1023];
}

// ssrc[j] = src of j-th dst-sorted edge; wsb[j] = 8 bf16 weights (t0..t7)
__global__ __launch_bounds__(256) void fillA_kernel(
    const int* __restrict__ src, const int* __restrict__ dst,
    const float* __restrict__ w, int* __restrict__ cursor,
    int* __restrict__ ssrc, uint4* __restrict__ wsb, int E)
{
    int e = blockIdx.x * 256 + threadIdx.x;
    if (e >= E) return;
    int d = dst[e];
    int j = atomicAdd(&cursor[d], 1);
    ssrc[j] = src[e];
    uint4 p;
    p.x = f2bfu(w[(size_t)0 * E + e]) | (f2bfu(w[(size_t)1 * E + e]) << 16);
    p.y = f2bfu(w[(size_t)2 * E + e]) | (f2bfu(w[(size_t)3 * E + e]) << 16);
    p.z = f2bfu(w[(size_t)4 * E + e]) | (f2bfu(w[(size_t)5 * E + e]) << 16);
    p.w = f2bfu(w[(size_t)6 * E + e]) | (f2bfu(w[(size_t)7 * E + e]) << 16);
    wsb[j] = p;
}

// -------- aggregate (depth-2 pipelined gather) + norm-on-the-fly + GEMM + stats
// r11-proven structure (best measured: 221.6 us total).
// MODE 0: hf (N,F) f32, broadcast over t. MODE 1: hb bf16-packed raw,
// apply relu(x*cA[f]+cB[f]). OUTB 1: bf16-packed out; OUTB 0: f32 out.
template <int MODE, int OUTB>
__global__ __launch_bounds__(256) void agg_gemm6_kernel(
    const float* __restrict__ hf, const uint4* __restrict__ hb,
    const float* __restrict__ coefIn,
    const int* __restrict__ rowptr, const int* __restrict__ ssrc,
    const uint4* __restrict__ wsb,
    const float* __restrict__ W, const float* __restrict__ bias,
    unsigned int* __restrict__ outU, float* __restrict__ outF,
    float* __restrict__ stats)
{
    __shared__ float Wt[FD * WS];          // Wt[k*33 + o], padded
    __shared__ float red[512];
    __shared__ float pacc[8 * TF * FD];    // [slot][t][f]
    int tid = threadIdx.x;
    int slot = tid >> 5, f = tid & 31;
    {   // stage W transposed; padded stride -> conflict-free banks
        int ff = tid & 31;
        Wt[ff * WS + (tid >> 5)] = W[tid];
        Wt[ff * WS + ((tid + 256) >> 5)] = W[tid + 256];
        Wt[ff * WS + ((tid + 512) >> 5)] = W[tid + 512];
        Wt[ff * WS + ((tid + 768) >> 5)] = W[tid + 768];
    }
    float cA = 0.f, cB = 0.f;
    if (MODE == 1) { cA = coefIn[f]; cB = coefIn[FD + f]; }

    int node = blockIdx.x;
    int rs = rowptr[node], re = rowptr[node + 1];

    float acc[TF];
    #pragma unroll
    for (int t = 0; t < TF; ++t) acc[t] = 0.f;

    // depth-2 pipelined gather: while computing edge j, the loads for edge
    // j+8 (wsb, h-row) are already in flight; ssrc is prefetched 2 ahead so
    // the h-address for the next iteration is always known at iter start.
    int j = rs + slot;
    if (j < re) {
        int s0 = ssrc[j];
        int j1 = j + 8;
        int s1 = (j1 < re) ? ssrc[j1] : 0;
        uint4 wp = wsb[j];
        float  hf0 = 0.f; uint4 hp0 = {0u,0u,0u,0u};
        if (MODE == 0) hf0 = hf[(size_t)s0 * FD + f];
        else           hp0 = hb[(size_t)s0 * FD + f];

        for (; j < re; j += 8, j1 += 8) {
            // issue next-iteration loads first (independent of compute)
            int j2 = j1 + 8;
            int s2 = (j2 < re) ? ssrc[j2] : 0;
            uint4 wp_n = {0u,0u,0u,0u};
            if (j1 < re) wp_n = wsb[j1];
            float hf_n = 0.f; uint4 hp_n = {0u,0u,0u,0u};
            if (MODE == 0) hf_n = hf[(size_t)s1 * FD + f];   // s1 always valid (0 if clamped)
            else           hp_n = hb[(size_t)s1 * FD + f];

            // compute on current (loaded last iteration)
            unsigned int ww[4] = { wp.x, wp.y, wp.z, wp.w };
            if (MODE == 0) {
                #pragma unroll
                for (int t = 0; t < TF; ++t)
                    acc[t] = fmaf(bfx(ww[t >> 1], t & 1), hf0, acc[t]);
            } else {
                unsigned int hw[4] = { hp0.x, hp0.y, hp0.z, hp0.w };
                #pragma unroll
                for (int t = 0; t < TF; ++t) {
                    float hr = bfx(hw[t >> 1], t & 1);
                    float hn = fmaxf(0.f, fmaf(hr, cA, cB));
                    acc[t] = fmaf(bfx(ww[t >> 1], t & 1), hn, acc[t]);
                }
            }
            // rotate pipeline
            s1 = s2; wp = wp_n; hf0 = hf_n; hp0 = hp_n;
        }
    }

    // cross-slot reduction: pacc[slot][t][f]
    #pragma unroll
    for (int t = 0; t < TF; ++t)
        pacc[slot * (TF * FD) + t * FD + f] = acc[t];
    __syncthreads();
    int t2 = tid >> 5;                      // reinterpret thread as (t, f)
    float asum = 0.f;
    #pragma unroll
    for (int sl = 0; sl < 8; ++sl)
        asum += pacc[sl * (TF * FD) + t2 * FD + f];
    red[tid] = asum;
    __syncthreads();

    float oval = bias[f];
    #pragma unroll
    for (int k = 0; k < FD; ++k)
        oval = fmaf(red[t2 * FD + k], Wt[k * WS + f], oval);
    if (!OUTB)
        outF[(size_t)node * (TF * FD) + tid] = oval;   // raw f32

    __syncthreads();                        // done reading red/Wt
    red[tid] = oval;
    red[256 + tid] = oval * oval;
    __syncthreads();
    if (OUTB) {
        // pack bf16: uint q of node row f holds t=2q (lo), t=2q+1 (hi)
        if (tid < 128) {
            int ff = tid >> 2, q = tid & 3;
            unsigned int lo = f2bfu(red[(q * 2) * FD + ff]);
            unsigned int hi = f2bfu(red[(q * 2 + 1) * FD + ff]);
            outU[(size_t)node * 128 + ff * 4 + q] = lo | (hi << 16);
        }
        __syncthreads();
    }
    #pragma unroll
    for (int stride = 128; stride >= 32; stride >>= 1) {
        if (tid < stride) {
            red[tid] += red[tid + stride];
            red[256 + tid] += red[256 + tid + stride];
        }
        __syncthreads();
    }
    if (tid < 32) {
        int slot2 = blockIdx.x & 31;
        atomAddF(&stats[slot2 * 64 + tid], red[tid]);
        atomAddF(&stats[slot2 * 64 + 32 + tid], red[256 + tid]);
    }
}

__global__ void finalize_kernel(const float* __restrict__ stats,
                                const float* __restrict__ gamma,
                                const float* __restrict__ beta,
                                float* __restrict__ coef, float inv_count)
{
    int o = threadIdx.x;               // 32 threads
    float s = 0.f, sq = 0.f;
    #pragma unroll
    for (int k = 0; k < 32; ++k) { s += stats[k * 64 + o]; sq += stats[k * 64 + 32 + o]; }
    float mean = s * inv_count;
    float var  = sq * inv_count - mean * mean;
    float sc   = gamma[o] * rsqrtf(var + EPSV);
    coef[o]      = sc;
    coef[FD + o] = beta[o] - mean * sc;
}

__global__ __launch_bounds__(256) void norm_relu_kernel(
    float* __restrict__ x, const float* __restrict__ coef, int n4)
{
    int gid = blockIdx.x * 256 + threadIdx.x;
    if (gid >= n4) return;
    float4 v = ((const float4*)x)[gid];
    int o = (gid * 4) & 31;
    float4 r;
    r.x = fmaxf(0.f, fmaf(v.x, coef[o],     coef[32 + o]));
    r.y = fmaxf(0.f, fmaf(v.y, coef[o + 1], coef[33 + o]));
    r.z = fmaxf(0.f, fmaf(v.z, coef[o + 2], coef[34 + o]));
    r.w = fmaxf(0.f, fmaf(v.w, coef[o + 3], coef[35 + o]));
    ((float4*)x)[gid] = r;
}

// ------------------------------------------------ fallback (atomic scatter)
__global__ __launch_bounds__(256) void scatter0_kernel(
    const float* __restrict__ h, const float* __restrict__ w,
    const int* __restrict__ src, const int* __restrict__ dst,
    float* __restrict__ agg, int E)
{
    int gid = blockIdx.x * 256 + threadIdx.x;
    int e = gid >> 5;
    if (e >= E) return;
    int f = gid & 31;
    int s = src[e], d = dst[e];
    float hv = h[(size_t)s * FD + f];
    float* aggd = agg + (size_t)d * (TF * FD) + f;
    #pragma unroll
    for (int t = 0; t < TF; ++t)
        atomAddF(aggd + t * FD, w[(size_t)t * E + e] * hv);
}

__global__ __launch_bounds__(256) void scatterL_kernel(
    const float* __restrict__ h, const float* __restrict__ w,
    const int* __restrict__ src, const int* __restrict__ dst,
    float* __restrict__ agg, int E)
{
    int gid = blockIdx.x * 256 + threadIdx.x;
    int e = gid >> 5;
    if (e >= E) return;
    int f = gid & 31;
    int s = src[e], d = dst[e];
    const float* hs = h + (size_t)s * (TF * FD) + f;
    float* aggd = agg + (size_t)d * (TF * FD) + f;
    #pragma unroll
    for (int t = 0; t < TF; ++t)
        atomAddF(aggd + t * FD, w[(size_t)t * E + e] * hs[t * FD]);
}

__global__ __launch_bounds__(256) void gemm_stats_kernel(
    const float* __restrict__ agg, const float* __restrict__ W,
    const float* __restrict__ bias, float* __restrict__ out,
    float* __restrict__ stats, int nrows)
{
    __shared__ float Wt[FD * FD];
    __shared__ float rows[8 * FD];
    int tid = threadIdx.x;
    for (int i = tid; i < FD * FD; i += 256) {
        int o = i >> 5, f = i & 31;
        Wt[f * FD + o] = W[i];
    }
    int o = tid & 31;
    int r = tid >> 5;
    float b = bias[o];
    float sum = 0.f, sumsq = 0.f;
    int ngroups = (nrows + 7) >> 3;
    for (int g = blockIdx.x; g < ngroups; g += gridDim.x) {
        int row0 = g * 8;
        __syncthreads();
        int idx = row0 * FD + tid;
        rows[tid] = (idx < nrows * FD) ? agg[idx] : 0.f;
        __syncthreads();
        int row = row0 + r;
        if (row < nrows) {
            float acc = b;
            #pragma unroll
            for (int f2 = 0; f2 < FD; ++f2)
                acc = fmaf(rows[r * FD + f2], Wt[f2 * FD + o], acc);
            out[(size_t)row * FD + o] = acc;
            sum += acc;
            sumsq += acc * acc;
        }
    }
    __syncthreads();
    rows[tid] = sum;
    Wt[tid] = sumsq;
    __syncthreads();
    for (int stride = 128; stride >= 32; stride >>= 1) {
        if (tid < stride) { rows[tid] += rows[tid + stride]; Wt[tid] += Wt[tid + stride]; }
        __syncthreads();
    }
    if (tid < 32) {
        int slot = blockIdx.x & 31;
        atomAddF(&stats[slot * 64 + tid], rows[tid]);
        atomAddF(&stats[slot * 64 + 32 + tid], Wt[tid]);
    }
}

// ----------------------------------------------------------------- launch
extern "C" void kernel_launch(void* const* d_in, const int* in_sizes, int n_in,
                              void* d_out, int out_size, void* d_ws, size_t ws_size,
                              hipStream_t stream)
{
    const float* nf  = (const float*)d_in[0];
    const float* wgt = (const float*)d_in[1];
    const int*   src = (const int*)d_in[2];
    const int*   dst = (const int*)d_in[3];
    const float* Ws  = (const float*)d_in[4];
    const float* bs  = (const float*)d_in[5];
    const float* gam = (const float*)d_in[6];
    const float* bet = (const float*)d_in[7];

    int E  = in_sizes[2];
    int Nn = in_sizes[0] / FD;
    int nrows = Nn * TF;
    int n4 = nrows * FD / 4;
    float inv_count = 1.0f / (float)nrows;
    float* out = (float*)d_out;

    // layout (int units): counts Nn | stats 3*2048 | coef 3*64 | cursor Nn |
    // rowptr Nn+4 | ssrc E | wsb 4E(uint4) | hb0 128Nn | hb1 128Nn
    size_t offCounts = 0;
    size_t offStats  = offCounts + (size_t)Nn;       // memset covers counts+stats
    size_t offCoef   = offStats + 3 * 2048;
    size_t offCursor = offCoef + 3 * 64;
    size_t offRowptr = offCursor + (size_t)Nn;
    size_t offSsrc   = offRowptr + (size_t)Nn + 4;
    size_t offWsb    = (offSsrc + (size_t)E + 3) & ~(size_t)3;   // 16B align
    size_t offHb0    = offWsb + 4 * (size_t)E;
    size_t offHb1    = offHb0 + 128 * (size_t)Nn;
    size_t needW     = (offHb1 + 128 * (size_t)Nn) * 4;

    int eb = (E + 255) / 256;

    if (ws_size >= needW) {
        int*          base   = (int*)d_ws;
        int*          counts = base + offCounts;
        float*        stats  = (float*)(base + offStats);
        float*        coef   = (float*)(base + offCoef);
        int*          cursor = base + offCursor;
        int*          rowptr = base + offRowptr;
        int*          ssrc   = base + offSsrc;
        uint4*        wsb    = (uint4*)(base + offWsb);
        unsigned int* hb0    = (unsigned int*)(base + offHb0);
        unsigned int* hb1    = (unsigned int*)(base + offHb1);

        // one memset: counts + all 3 stats blocks (adjacent)
        hipMemsetAsync(counts, 0, ((size_t)Nn + 3 * 2048) * sizeof(int), stream);
        hist_kernel<<<eb, 256, 0, stream>>>(dst, counts, E);
        scan_kernel<<<1, 1024, 0, stream>>>(counts, rowptr, cursor, Nn);
        fillA_kernel<<<eb, 256, 0, stream>>>(src, dst, wgt, cursor, ssrc, wsb, E);

        // L0: nf(f32) -> hb0 (bf16 raw)
        agg_gemm6_kernel<0, 1><<<Nn, 256, 0, stream>>>(
            nf, nullptr, nullptr, rowptr, ssrc, wsb, Ws, bs,
            hb0, nullptr, stats);
        finalize_kernel<<<1, 32, 0, stream>>>(stats, gam, bet, coef, inv_count);
        // L1: hb0 -> hb1 (bf16 raw), norm0 via coef0
        agg_gemm6_kernel<1, 1><<<Nn, 256, 0, stream>>>(
            nullptr, (const uint4*)hb0, coef, rowptr, ssrc, wsb,
            Ws + FD * FD, bs + FD, hb1, nullptr, stats + 2048);
        finalize_kernel<<<1, 32, 0, stream>>>(
            stats + 2048, gam + FD, bet + FD, coef + 64, inv_count);
        // L2: hb1 -> out (f32 raw), norm1 via coef1
        agg_gemm6_kernel<1, 0><<<Nn, 256, 0, stream>>>(
            nullptr, (const uint4*)hb1, coef + 64, rowptr, ssrc, wsb,
            Ws + 2 * FD * FD, bs + 2 * FD, nullptr, out, stats + 2 * 2048);
        finalize_kernel<<<1, 32, 0, stream>>>(
            stats + 2 * 2048, gam + 2 * FD, bet + 2 * FD, coef + 2 * 64, inv_count);
        // final norm+relu via coef2
        norm_relu_kernel<<<(n4 + 255) / 256, 256, 0, stream>>>(out, coef + 2 * 64, n4);
    } else {
        // fallback: round-0 atomic scatter path (proven)
        float* agg   = (float*)d_ws;
        float* stats = agg + (size_t)nrows * FD;
        float* coef  = stats + 2048;
        int scatterBlocks = (E * 32 + 255) / 256;
        for (int l = 0; l < 3; ++l) {
            hipMemsetAsync(agg, 0, (size_t)nrows * FD * sizeof(float), stream);
            hipMemsetAsync(stats, 0, 2048 * sizeof(float), stream);
            if (l == 0)
                scatter0_kernel<<<scatterBlocks, 256, 0, stream>>>(nf, wgt, src, dst, agg, E);
            else
                scatterL_kernel<<<scatterBlocks, 256, 0, stream>>>(out, wgt, src, dst, agg, E);
            gemm_stats_kernel<<<2048, 256, 0, stream>>>(
                agg, Ws + l * FD * FD, bs + l * FD, out, stats, nrows);
            finalize_kernel<<<1, 32, 0, stream>>>(
                stats, gam + l * FD, bet + l * FD, coef, inv_count);
            norm_relu_kernel<<<(n4 + 255) / 256, 256, 0, stream>>>(out, coef, n4);
        }
    }
}